// Round 9
// baseline (714.179 us; speedup 1.0000x reference)
//
#include <hip/hip_runtime.h>

#define B_ 8
#define N_ 4096
#define K_ 16
#define C_ 64
#define NK_ (N_*K_)            // 65536
#define M_ (B_*N_*K_)          // 524288
#define BN_EPS_ 0.001f
#define CH_ 16                 // knn candidate chunks
#define CS_ (N_/CH_)           // 256 candidates per chunk
#define Q_ (B_*N_)             // 32768 queries
#define NB1_ (M_/128)          // 4096 blocks in layer kernels
#define NB0_ (M_/256)          // 2048 blocks in stats0
#define R1_ (NB1_*4)           // 16384 wave-partial rows (layer kernels)

typedef short bf16x8 __attribute__((ext_vector_type(8)));   // 8 bf16 = 4 VGPRs
typedef float f32x4 __attribute__((ext_vector_type(4)));

// bf16 round-to-nearest-even (no NaN inputs in this pipeline)
static __device__ __forceinline__ unsigned short f2bf(float x) {
  unsigned u = __float_as_uint(x);
  unsigned r = (u + 0x7FFFu + ((u >> 16) & 1u)) >> 16;
  return (unsigned short)r;
}
static __device__ __forceinline__ unsigned pk2bf(float a, float b) {
  return (unsigned)f2bf(a) | ((unsigned)f2bf(b) << 16);
}

// ---------------- pack points (B,3,N) -> float4 (B*N) ----------------
__global__ __launch_bounds__(256) void pack_pts(const float* __restrict__ p,
                                                float4* __restrict__ pf4) {
  int i = blockIdx.x * 256 + threadIdx.x;
  int b = i >> 12;
  int n = i & (N_ - 1);
  const float* base = p + (size_t)b * 3 * N_;
  pf4[i] = make_float4(base[n], base[N_ + n], base[2 * N_ + n], 0.f);
}

// ---------------- W (128x128 fp32) -> bf16 same layout ----------------
__global__ __launch_bounds__(256) void wcvt(const float* __restrict__ W,
                                            unsigned short* __restrict__ Wb) {
  int i = blockIdx.x * 256 + threadIdx.x;   // 16384
  Wb[i] = f2bf(W[i]);
}

// ---------------- w0at[d][o] = W0[o][d], d<3 ----------------
__global__ void make_w0at(const float* __restrict__ W0, float* __restrict__ w0at) {
  int o = threadIdx.x;  // 128
  for (int d = 0; d < 3; ++d) w0at[d * 128 + o] = W0[o * 131 + d];
}

// ================= KNN, candidate-split 16 ways =================
__global__ __launch_bounds__(64) void knn_part(const float4* __restrict__ p1f4,
                                               const float4* __restrict__ p2f4,
                                               float* __restrict__ pvals) {
  int lane = threadIdx.x;
  int blk = blockIdx.x;            // chunk fastest: b(8) x grp(64) x chunk(16)
  int chunk = blk & (CH_ - 1);
  int grp = (blk >> 4) & 63;
  int b = blk >> 10;
  int n1 = (grp << 6) + lane;
  int q = (b << 12) + n1;
  float4 qv = p1f4[q];
  float ax = qv.x, ay = qv.y, az = qv.z;
  const float4* pb = p2f4 + ((size_t)b << 12) + chunk * CS_;

  float s[16];
  #pragma unroll
  for (int i = 0; i < 16; ++i) s[i] = 3.0e38f;   // desc sorted; s[0]=16th smallest

  #pragma unroll 8
  for (int t = 0; t < CS_; ++t) {
    float4 c = pb[t];              // wave-uniform -> scalar load
    float dx = ax - c.x, dy = ay - c.y, dz = az - c.z;
    float d = __fadd_rn(__fadd_rn(__fmul_rn(dx, dx), __fmul_rn(dy, dy)), __fmul_rn(dz, dz));
    #pragma unroll
    for (int i = 0; i < 15; ++i) s[i] = __builtin_amdgcn_fmed3f(s[i], s[i + 1], d);
    s[15] = fminf(s[15], d);
  }
  #pragma unroll
  for (int i = 0; i < 16; ++i) pvals[(size_t)(chunk * 16 + i) * Q_ + q] = s[i];
}

__global__ __launch_bounds__(256) void knn_merge(const float* __restrict__ pvals,
                                                 float* __restrict__ Tarr) {
  int q = blockIdx.x * 256 + threadIdx.x;
  float s[16];
  #pragma unroll
  for (int i = 0; i < 16; ++i) s[i] = 3.0e38f;
  #pragma unroll 8
  for (int t = 0; t < CH_ * 16; ++t) {
    float d = pvals[(size_t)t * Q_ + q];
    #pragma unroll
    for (int i = 0; i < 15; ++i) s[i] = __builtin_amdgcn_fmed3f(s[i], s[i + 1], d);
    s[15] = fminf(s[15], d);
  }
  Tarr[q] = s[0];
}

__global__ __launch_bounds__(64) void knn_cand(const float4* __restrict__ p1f4,
                                               const float4* __restrict__ p2f4,
                                               const float* __restrict__ Tarr,
                                               int* __restrict__ cidx,
                                               int* __restrict__ ccnt) {
  int lane = threadIdx.x;
  int blk = blockIdx.x;
  int chunk = blk & (CH_ - 1);
  int grp = (blk >> 4) & 63;
  int b = blk >> 10;
  int n1 = (grp << 6) + lane;
  int q = (b << 12) + n1;
  float4 qq = p1f4[q];
  float ax = qq.x, ay = qq.y, az = qq.z;
  const float4* pb = p2f4 + ((size_t)b << 12) + chunk * CS_;
  float T = Tarr[q];
  int cnt = 0;
  int base = (q * CH_ + chunk) * 16;
  #pragma unroll 4
  for (int t = 0; t < CS_; ++t) {
    float4 c = pb[t];
    float dx = ax - c.x, dy = ay - c.y, dz = az - c.z;
    float d = __fadd_rn(__fadd_rn(__fmul_rn(dx, dx), __fmul_rn(dy, dy)), __fmul_rn(dz, dz));
    if (d <= T && cnt < 16) { cidx[base + cnt] = chunk * CS_ + t; ++cnt; }
  }
  ccnt[q * CH_ + chunk] = cnt;
}

__global__ __launch_bounds__(256) void knn_combine(const int* __restrict__ cidx,
                                                   const int* __restrict__ ccnt,
                                                   int* __restrict__ idxout) {
  int q = blockIdx.x * 256 + threadIdx.x;
  int tot = 0;
  int ob = q * 16;
  for (int c = 0; c < CH_; ++c) {
    int m = ccnt[q * CH_ + c];
    const int* src = cidx + (size_t)(q * CH_ + c) * 16;
    for (int i = 0; i < m && tot < 16; ++i) idxout[ob + tot++] = src[i];
  }
}

// ---------------- P[bn][o] = sum_c W0[o][coff+c] * f[b][c][n] (+bias) ----------------
__global__ __launch_bounds__(256) void pkern(const float* __restrict__ f,
                                             const float* __restrict__ W0,
                                             const float* __restrict__ bias,
                                             float* __restrict__ P, int coff) {
  __shared__ float fx[32 * 65];
  __shared__ __align__(16) float Wl[64 * 132];
  int tid = threadIdx.x;
  int bn0 = blockIdx.x * 32;
  int b = bn0 >> 12, nb0 = bn0 & (N_ - 1);

  for (int u = tid; u < 32 * 64; u += 256) {
    int c = u >> 5, nl = u & 31;
    fx[nl * 65 + c] = f[((size_t)b * C_ + c) * N_ + nb0 + nl];
  }
  for (int u = tid; u < 128 * 64; u += 256) {
    int o = u >> 6, c = u & 63;
    Wl[c * 132 + o] = W0[o * 131 + coff + c];
  }
  __syncthreads();

  int og = tid & 15, np_ = tid >> 4;
  int o0 = og * 8;
  int na = np_ * 2, nb = na + 1;
  float acc0[8], acc1[8];
  #pragma unroll
  for (int j = 0; j < 8; ++j) {
    float bv = bias ? bias[o0 + j] : 0.f;
    acc0[j] = bv; acc1[j] = bv;
  }
  for (int c = 0; c < 64; ++c) {
    float x0 = fx[na * 65 + c], x1 = fx[nb * 65 + c];
    float4 wa = *(const float4*)&Wl[c * 132 + o0];
    float4 wb = *(const float4*)&Wl[c * 132 + o0 + 4];
    float w[8] = {wa.x, wa.y, wa.z, wa.w, wb.x, wb.y, wb.z, wb.w};
    #pragma unroll
    for (int j = 0; j < 8; ++j) {
      acc0[j] = fmaf(x0, w[j], acc0[j]);
      acc1[j] = fmaf(x1, w[j], acc1[j]);
    }
  }
  float* Pa = P + (size_t)(bn0 + na) * 128 + o0;
  float* Pb = P + (size_t)(bn0 + nb) * 128 + o0;
  *(float4*)Pa = make_float4(acc0[0], acc0[1], acc0[2], acc0[3]);
  *(float4*)(Pa + 4) = make_float4(acc0[4], acc0[5], acc0[6], acc0[7]);
  *(float4*)Pb = make_float4(acc1[0], acc1[1], acc1[2], acc1[3]);
  *(float4*)(Pb + 4) = make_float4(acc1[4], acc1[5], acc1[6], acc1[7]);
}

// ---------------- BN0 stats: partials to part[blk*256 + s] (contiguous 1KB/block) ----------------
__global__ __launch_bounds__(256) void stats0_kernel(
    const float* __restrict__ P1, const float* __restrict__ P2,
    const int* __restrict__ idx, const float4* __restrict__ p1f4,
    const float4* __restrict__ p2f4, const float* __restrict__ w0at,
    float* __restrict__ part) {
  int tid = threadIdx.x;
  int c = tid & 127, h = tid >> 7;
  float w0 = w0at[c], w1 = w0at[128 + c], w2 = w0at[256 + c];
  float sum = 0.f, sq = 0.f;
  int rbase = blockIdx.x * 256 + h * 128;
  for (int i = 0; i < 128; ++i) {
    int r = rbase + i;
    int b = r >> 16;
    int nk = r & (NK_ - 1);
    int n = nk >> 4;
    int j = idx[r];
    float4 pq = p1f4[(b << 12) + n];
    float4 pj = p2f4[(b << 12) + j];
    float rx = pj.x - pq.x, ry = pj.y - pq.y, rz = pj.z - pq.z;
    float a0 = w0 * rx + w1 * ry + w2 * rz;
    float x = P1[(size_t)((b << 12) + n) * 128 + c] +
              P2[(size_t)((b << 12) + j) * 128 + c] + a0;
    sum += x;
    sq = fmaf(x, x, sq);
  }
  __shared__ float red[256 * 2];
  red[tid * 2] = sum;
  red[tid * 2 + 1] = sq;
  __syncthreads();
  if (h == 0) {
    float a = sum + red[(tid + 128) * 2];
    float q2 = sq + red[(tid + 128) * 2 + 1];
    part[(size_t)blockIdx.x * 256 + c] = a;
    part[(size_t)blockIdx.x * 256 + 128 + c] = q2;
  }
}

// ---------------- two-stage coalesced partial reduction ----------------
__global__ __launch_bounds__(256) void reduce1(const float* __restrict__ part,
                                               int R, float* __restrict__ mid) {
  int j = blockIdx.x;          // 64 blocks
  int t = threadIdx.x;
  int per = R / 64;
  const float* src = part + (size_t)j * per * 256;
  float a = 0.f;
  for (int i = 0; i < per; ++i) a += src[(size_t)i * 256 + t];
  mid[j * 256 + t] = a;
}
__global__ __launch_bounds__(256) void reduce2(const float* __restrict__ mid,
                                               float* __restrict__ statso) {
  int t = threadIdx.x;
  float a = 0.f;
  #pragma unroll
  for (int j = 0; j < 64; ++j) a += mid[j * 256 + t];
  statso[t] = a;
}

// ---------------- BN finalize ----------------
__global__ void bnfin_kernel(const float* __restrict__ stats, const float* __restrict__ gamma,
                             const float* __restrict__ beta, float* __restrict__ bnp) {
  int o = threadIdx.x;
  const float invM = 1.0f / (float)M_;
  float mean = stats[o] * invM;
  float var = stats[128 + o] * invM - mean * mean;
  float s = gamma[o] * rsqrtf(var + BN_EPS_);
  bnp[o] = s;
  bnp[128 + o] = beta[o] - mean * s;
}

// ---------------- layer1 (MFMA): assemble x0 -> BN0+relu -> bf16 GEMM W1 -> x1(bf16) + wave-partials ----------------
__global__ __launch_bounds__(256) void layer1_mfma(
    const float* __restrict__ P1, const float* __restrict__ P2,
    const int* __restrict__ idx, const float4* __restrict__ p1f4,
    const float4* __restrict__ p2f4, const float* __restrict__ w0at,
    const float* __restrict__ bnp0, const unsigned short* __restrict__ W1b,
    const float* __restrict__ b1, unsigned short* __restrict__ x1out,
    float* __restrict__ part) {
  __shared__ __align__(16) unsigned short Xs[128 * 136];   // [row][k], pad 8 bf16
  int tid = threadIdx.x;
  int R0 = blockIdx.x * 128;
  int b = R0 >> 16;
  int n0 = (R0 & (NK_ - 1)) >> 4;

  int cc = (tid & 15) * 8;     // column base (fixed across passes)
  int r0l = tid >> 4;          // row within pass group [0,16)

  // ---- stage X (bf16), coalesced, MLP-hoisted ----
  {
    float wxv[8], wyv[8], wzv[8], svv[8], tvv[8];
    *(float4*)&wxv[0] = *(const float4*)(w0at + cc);       *(float4*)&wxv[4] = *(const float4*)(w0at + cc + 4);
    *(float4*)&wyv[0] = *(const float4*)(w0at + 128 + cc); *(float4*)&wyv[4] = *(const float4*)(w0at + 132 + cc);
    *(float4*)&wzv[0] = *(const float4*)(w0at + 256 + cc); *(float4*)&wzv[4] = *(const float4*)(w0at + 260 + cc);
    *(float4*)&svv[0] = *(const float4*)(bnp0 + cc);       *(float4*)&svv[4] = *(const float4*)(bnp0 + cc + 4);
    *(float4*)&tvv[0] = *(const float4*)(bnp0 + 128 + cc); *(float4*)&tvv[4] = *(const float4*)(bnp0 + 132 + cc);
    int jj[8];
    #pragma unroll
    for (int p = 0; p < 8; ++p) jj[p] = idx[R0 + r0l + p * 16];
    float4 pq8[8];
    #pragma unroll
    for (int p = 0; p < 8; ++p) pq8[p] = p1f4[(b << 12) + n0 + p];
    #pragma unroll
    for (int g = 0; g < 4; ++g) {
      float4 pjv[2], p1a[2], p1b[2], p2a[2], p2b[2];
      #pragma unroll
      for (int t = 0; t < 2; ++t) {
        int p = g * 2 + t;
        pjv[t] = p2f4[(b << 12) + jj[p]];
        const float* P1r = P1 + (size_t)((b << 12) + n0 + p) * 128 + cc;
        const float* P2r = P2 + (size_t)((b << 12) + jj[p]) * 128 + cc;
        p1a[t] = *(const float4*)P1r; p1b[t] = *(const float4*)(P1r + 4);
        p2a[t] = *(const float4*)P2r; p2b[t] = *(const float4*)(P2r + 4);
      }
      #pragma unroll
      for (int t = 0; t < 2; ++t) {
        int p = g * 2 + t;
        float rx = pjv[t].x - pq8[p].x, ry = pjv[t].y - pq8[p].y, rz = pjv[t].z - pq8[p].z;
        float p1v[8], p2v[8];
        *(float4*)&p1v[0] = p1a[t]; *(float4*)&p1v[4] = p1b[t];
        *(float4*)&p2v[0] = p2a[t]; *(float4*)&p2v[4] = p2b[t];
        float y[8];
        #pragma unroll
        for (int u = 0; u < 8; ++u) {
          float x = p1v[u] + p2v[u] + wxv[u] * rx + wyv[u] * ry + wzv[u] * rz;
          y[u] = fmaxf(fmaf(svv[u], x, tvv[u]), 0.f);
        }
        uint4 pk;
        pk.x = pk2bf(y[0], y[1]); pk.y = pk2bf(y[2], y[3]);
        pk.z = pk2bf(y[4], y[5]); pk.w = pk2bf(y[6], y[7]);
        *(uint4*)&Xs[(r0l + p * 16) * 136 + cc] = pk;
      }
    }
  }
  __syncthreads();

  // ---- MFMA (q-loop fully unrolled: all B-frag loads in flight early) ----
  int w = tid >> 6, lane = tid & 63;
  int m16 = lane & 15, qd = lane >> 4;
  f32x4 acc[2][8];
  #pragma unroll
  for (int mt = 0; mt < 2; ++mt)
    #pragma unroll
    for (int nt = 0; nt < 8; ++nt) acc[mt][nt] = (f32x4){0.f, 0.f, 0.f, 0.f};

  const unsigned short* Ab = &Xs[(w * 32 + m16) * 136 + qd * 8];
  const unsigned short* Bb = W1b + m16 * 128 + qd * 8;
  #pragma unroll
  for (int q = 0; q < 4; ++q) {
    bf16x8 A0 = *(const bf16x8*)(Ab + q * 32);
    bf16x8 A1 = *(const bf16x8*)(Ab + 16 * 136 + q * 32);
    #pragma unroll
    for (int nt = 0; nt < 8; ++nt) {
      bf16x8 Bv = *(const bf16x8*)(Bb + nt * 16 * 128 + q * 32);
      acc[0][nt] = __builtin_amdgcn_mfma_f32_16x16x32_bf16(A0, Bv, acc[0][nt], 0, 0, 0);
      acc[1][nt] = __builtin_amdgcn_mfma_f32_16x16x32_bf16(A1, Bv, acc[1][nt], 0, 0, 0);
    }
  }
  __syncthreads();   // Xs reads done; reuse for D-transpose

  // ---- epilogue: bias + stats (registers), D -> Xs (bf16), wave-level partials ----
  float ssum[8], ssq[8];
  #pragma unroll
  for (int nt = 0; nt < 8; ++nt) { ssum[nt] = 0.f; ssq[nt] = 0.f; }
  #pragma unroll
  for (int nt = 0; nt < 8; ++nt) {
    int col = nt * 16 + m16;
    float bb = b1[col];
    #pragma unroll
    for (int mt = 0; mt < 2; ++mt) {
      #pragma unroll
      for (int rg = 0; rg < 4; ++rg) {
        float y = acc[mt][nt][rg] + bb;
        ssum[nt] += y;
        ssq[nt] = fmaf(y, y, ssq[nt]);
        Xs[(w * 32 + mt * 16 + qd * 4 + rg) * 136 + col] = f2bf(y);
      }
    }
  }
  #pragma unroll
  for (int nt = 0; nt < 8; ++nt) {
    ssum[nt] += __shfl_xor(ssum[nt], 16);
    ssum[nt] += __shfl_xor(ssum[nt], 32);
    ssq[nt] += __shfl_xor(ssq[nt], 16);
    ssq[nt] += __shfl_xor(ssq[nt], 32);
  }
  if (lane < 16) {
    float* pw = part + (size_t)(blockIdx.x * 4 + w) * 256;
    #pragma unroll
    for (int nt = 0; nt < 8; ++nt) {
      pw[nt * 16 + lane] = ssum[nt];
      pw[128 + nt * 16 + lane] = ssq[nt];
    }
  }
  __syncthreads();   // D->Xs writes complete before cross-wave x1 reads

  // ---- coalesced x1 store from Xs ----
  #pragma unroll
  for (int p = 0; p < 8; ++p) {
    int rl = r0l + p * 16;
    uint4 v = *(const uint4*)&Xs[rl * 136 + cc];
    *(uint4*)(x1out + (size_t)(R0 + rl) * 128 + cc) = v;
  }
}

// ---------------- layer2 (MFMA): BN1+relu -> bf16 GEMM W2 -> k-max/min + wave-partials ----------------
__global__ __launch_bounds__(256) void layer2_mfma(
    const unsigned short* __restrict__ x1, const float* __restrict__ bnp1,
    const unsigned short* __restrict__ W2b, const float* __restrict__ b2,
    float* __restrict__ ymaxo, float* __restrict__ ymino,
    float* __restrict__ part) {
  __shared__ __align__(16) unsigned short Xs[128 * 136];
  int tid = threadIdx.x;
  int R0 = blockIdx.x * 128;
  int b = R0 >> 16;
  int n0 = (R0 & (NK_ - 1)) >> 4;

  int cc = (tid & 15) * 8;
  int r0l = tid >> 4;

  // ---- stage X (bf16): BN1+relu on x1 ----
  {
    float svv[8], tvv[8];
    *(float4*)&svv[0] = *(const float4*)(bnp1 + cc);       *(float4*)&svv[4] = *(const float4*)(bnp1 + cc + 4);
    *(float4*)&tvv[0] = *(const float4*)(bnp1 + 128 + cc); *(float4*)&tvv[4] = *(const float4*)(bnp1 + 132 + cc);
    #pragma unroll
    for (int g = 0; g < 2; ++g) {
      uint4 pv[4];
      #pragma unroll
      for (int t = 0; t < 4; ++t)
        pv[t] = *(const uint4*)(x1 + (size_t)(R0 + r0l + (g * 4 + t) * 16) * 128 + cc);
      #pragma unroll
      for (int t = 0; t < 4; ++t) {
        int rl = r0l + (g * 4 + t) * 16;
        float xv[8];
        xv[0] = __uint_as_float(pv[t].x << 16); xv[1] = __uint_as_float(pv[t].x & 0xFFFF0000u);
        xv[2] = __uint_as_float(pv[t].y << 16); xv[3] = __uint_as_float(pv[t].y & 0xFFFF0000u);
        xv[4] = __uint_as_float(pv[t].z << 16); xv[5] = __uint_as_float(pv[t].z & 0xFFFF0000u);
        xv[6] = __uint_as_float(pv[t].w << 16); xv[7] = __uint_as_float(pv[t].w & 0xFFFF0000u);
        float y[8];
        #pragma unroll
        for (int u = 0; u < 8; ++u) y[u] = fmaxf(fmaf(svv[u], xv[u], tvv[u]), 0.f);
        uint4 pk;
        pk.x = pk2bf(y[0], y[1]); pk.y = pk2bf(y[2], y[3]);
        pk.z = pk2bf(y[4], y[5]); pk.w = pk2bf(y[6], y[7]);
        *(uint4*)&Xs[rl * 136 + cc] = pk;
      }
    }
  }
  __syncthreads();

  int w = tid >> 6, lane = tid & 63;
  int m16 = lane & 15, qd = lane >> 4;
  f32x4 acc[2][8];
  #pragma unroll
  for (int mt = 0; mt < 2; ++mt)
    #pragma unroll
    for (int nt = 0; nt < 8; ++nt) acc[mt][nt] = (f32x4){0.f, 0.f, 0.f, 0.f};

  const unsigned short* Ab = &Xs[(w * 32 + m16) * 136 + qd * 8];
  const unsigned short* Bb = W2b + m16 * 128 + qd * 8;
  #pragma unroll
  for (int q = 0; q < 4; ++q) {
    bf16x8 A0 = *(const bf16x8*)(Ab + q * 32);
    bf16x8 A1 = *(const bf16x8*)(Ab + 16 * 136 + q * 32);
    #pragma unroll
    for (int nt = 0; nt < 8; ++nt) {
      bf16x8 Bv = *(const bf16x8*)(Bb + nt * 16 * 128 + q * 32);
      acc[0][nt] = __builtin_amdgcn_mfma_f32_16x16x32_bf16(A0, Bv, acc[0][nt], 0, 0, 0);
      acc[1][nt] = __builtin_amdgcn_mfma_f32_16x16x32_bf16(A1, Bv, acc[1][nt], 0, 0, 0);
    }
  }

  // ---- epilogue: bias, stats, k-max/min over 16 rows ----
  float ssum[8], ssq[8], mxv[2][8], mnv[2][8];
  #pragma unroll
  for (int nt = 0; nt < 8; ++nt) { ssum[nt] = 0.f; ssq[nt] = 0.f; }
  #pragma unroll
  for (int nt = 0; nt < 8; ++nt) {
    float bb = b2[nt * 16 + m16];
    #pragma unroll
    for (int mt = 0; mt < 2; ++mt) {
      float y0 = acc[mt][nt][0] + bb;
      float mx = y0, mn = y0, su = y0, sq = y0 * y0;
      #pragma unroll
      for (int rg = 1; rg < 4; ++rg) {
        float y = acc[mt][nt][rg] + bb;
        mx = fmaxf(mx, y); mn = fminf(mn, y);
        su += y; sq = fmaf(y, y, sq);
      }
      mxv[mt][nt] = mx; mnv[mt][nt] = mn;
      ssum[nt] += su; ssq[nt] += sq;
    }
  }
  #pragma unroll
  for (int nt = 0; nt < 8; ++nt)
    #pragma unroll
    for (int mt = 0; mt < 2; ++mt) {
      mxv[mt][nt] = fmaxf(mxv[mt][nt], __shfl_xor(mxv[mt][nt], 16));
      mxv[mt][nt] = fmaxf(mxv[mt][nt], __shfl_xor(mxv[mt][nt], 32));
      mnv[mt][nt] = fminf(mnv[mt][nt], __shfl_xor(mnv[mt][nt], 16));
      mnv[mt][nt] = fminf(mnv[mt][nt], __shfl_xor(mnv[mt][nt], 32));
    }
  if (lane < 16) {
    #pragma unroll
    for (int mt = 0; mt < 2; ++mt) {
      int n = n0 + w * 2 + mt;
      size_t base = ((size_t)(b << 12) + n) * 128;
      #pragma unroll
      for (int nt = 0; nt < 8; ++nt) {
        ymaxo[base + nt * 16 + lane] = mxv[mt][nt];
        ymino[base + nt * 16 + lane] = mnv[mt][nt];
      }
    }
  }
  #pragma unroll
  for (int nt = 0; nt < 8; ++nt) {
    ssum[nt] += __shfl_xor(ssum[nt], 16);
    ssum[nt] += __shfl_xor(ssum[nt], 32);
    ssq[nt] += __shfl_xor(ssq[nt], 16);
    ssq[nt] += __shfl_xor(ssq[nt], 32);
  }
  if (lane < 16) {
    float* pw = part + (size_t)(blockIdx.x * 4 + w) * 256;
    #pragma unroll
    for (int nt = 0; nt < 8; ++nt) {
      pw[nt * 16 + lane] = ssum[nt];
      pw[128 + nt * 16 + lane] = ssq[nt];
    }
  }
}

// ---------------- final: BN2+relu on max/min, transpose to (B,128,N) ----------------
__global__ __launch_bounds__(256) void final_kernel(const float* __restrict__ ymaxo,
                                                    const float* __restrict__ ymino,
                                                    const float* __restrict__ bnp2,
                                                    float* __restrict__ out) {
  __shared__ float T[64 * 129];
  int tid = threadIdx.x;
  int b = blockIdx.x >> 6;
  int n0 = (blockIdx.x & 63) * 64;
  for (int u = tid; u < 64 * 128; u += 256) {
    int nl = u >> 7, o = u & 127;
    size_t base = ((size_t)(b << 12) + n0 + nl) * 128 + o;
    float s = bnp2[o], t = bnp2[128 + o];
    float v = fmaf(s, (s >= 0.f ? ymaxo[base] : ymino[base]), t);
    T[nl * 129 + o] = fmaxf(v, 0.f);
  }
  __syncthreads();
  for (int u = tid; u < 64 * 128; u += 256) {
    int o = u >> 6, nl = u & 63;
    out[((size_t)b * 128 + o) * N_ + n0 + nl] = T[nl * 129 + o];
  }
}

extern "C" void kernel_launch(void* const* d_in, const int* in_sizes, int n_in,
                              void* d_out, int out_size, void* d_ws, size_t ws_size,
                              hipStream_t stream) {
  (void)in_sizes; (void)n_in; (void)out_size; (void)ws_size;
  const float* points1 = (const float*)d_in[0];
  const float* points2 = (const float*)d_in[1];
  const float* features1 = (const float*)d_in[2];
  const float* features2 = (const float*)d_in[3];
  const float* W0 = (const float*)d_in[4];
  const float* b0 = (const float*)d_in[5];
  const float* g0 = (const float*)d_in[6];
  const float* be0 = (const float*)d_in[7];
  const float* W1 = (const float*)d_in[8];
  const float* b1 = (const float*)d_in[9];
  const float* g1 = (const float*)d_in[10];
  const float* be1 = (const float*)d_in[11];
  const float* W2 = (const float*)d_in[12];
  const float* b2 = (const float*)d_in[13];
  const float* g2 = (const float*)d_in[14];
  const float* be2 = (const float*)d_in[15];
  float* out = (float*)d_out;

  char* ws = (char*)d_ws;
  size_t off = 0;
  auto alloc = [&](size_t bytes) -> void* {
    void* p = ws + off;
    off += (bytes + 255) & ~(size_t)255;
    return p;
  };
  int* idx = (int*)alloc((size_t)M_ * 4);
  float4* p1f4 = (float4*)alloc((size_t)B_ * N_ * 16);
  float4* p2f4 = (float4*)alloc((size_t)B_ * N_ * 16);
  float* P1 = (float*)alloc((size_t)B_ * N_ * 128 * 4);
  float* P2 = (float*)alloc((size_t)B_ * N_ * 128 * 4);
  unsigned short* W1b = (unsigned short*)alloc(128 * 128 * 2);
  unsigned short* W2b = (unsigned short*)alloc(128 * 128 * 2);
  float* w0at = (float*)alloc(3 * 128 * 4);
  float* stats = (float*)alloc(3 * 256 * 4);
  float* bnp = (float*)alloc(3 * 256 * 4);
  float* mid = (float*)alloc(3 * 64 * 256 * 4);                      // reduce stage-1 out
  unsigned short* x1 = (unsigned short*)alloc((size_t)M_ * 128 * 2);  // 128 MB (bf16)
  float* ymaxo = (float*)alloc((size_t)B_ * N_ * 128 * 4);
  float* ymino = (float*)alloc((size_t)B_ * N_ * 128 * 4);

  // KNN scratch aliased onto x1 (dead until layer1): ~66.2 MB < 128 MB
  float* pvals = (float*)x1;                                         // 32 MB
  int* cidx = (int*)((char*)x1 + (size_t)32 * 1024 * 1024);          // 32 MB
  int* ccnt = (int*)((char*)x1 + (size_t)64 * 1024 * 1024);          // 2 MB
  float* Tarr = (float*)((char*)x1 + (size_t)66 * 1024 * 1024);      // 128 KB

  // stats partials aliased onto dead buffers:
  //  part0 (2 MB,  stats0)  on ymaxo [first written in layer2]
  //  part1 (16 MB, layer1)  on ymino [first written in layer2]
  //  part2 (16 MB, layer2)  on P1    [dead after layer1]
  float* part0 = ymaxo;
  float* part1 = ymino;
  float* part2 = P1;

  pack_pts<<<B_ * N_ / 256, 256, 0, stream>>>(points1, p1f4);
  pack_pts<<<B_ * N_ / 256, 256, 0, stream>>>(points2, p2f4);
  wcvt<<<64, 256, 0, stream>>>(W1, W1b);
  wcvt<<<64, 256, 0, stream>>>(W2, W2b);
  make_w0at<<<1, 128, 0, stream>>>(W0, w0at);

  knn_part<<<B_ * 64 * CH_, 64, 0, stream>>>(p1f4, p2f4, pvals);
  knn_merge<<<Q_ / 256, 256, 0, stream>>>(pvals, Tarr);
  knn_cand<<<B_ * 64 * CH_, 64, 0, stream>>>(p1f4, p2f4, Tarr, cidx, ccnt);
  knn_combine<<<Q_ / 256, 256, 0, stream>>>(cidx, ccnt, idx);

  pkern<<<B_ * N_ / 32, 256, 0, stream>>>(features1, W0, b0, P1, 67);
  pkern<<<B_ * N_ / 32, 256, 0, stream>>>(features2, W0, nullptr, P2, 3);

  stats0_kernel<<<NB0_, 256, 0, stream>>>(P1, P2, idx, p1f4, p2f4, w0at, part0);
  reduce1<<<64, 256, 0, stream>>>(part0, NB0_, mid);
  reduce2<<<1, 256, 0, stream>>>(mid, stats);
  bnfin_kernel<<<1, 128, 0, stream>>>(stats, g0, be0, bnp);

  layer1_mfma<<<NB1_, 256, 0, stream>>>(P1, P2, idx, p1f4, p2f4, w0at, bnp,
                                        W1b, b1, x1, part1);
  reduce1<<<64, 256, 0, stream>>>(part1, R1_, mid + 64 * 256);
  reduce2<<<1, 256, 0, stream>>>(mid + 64 * 256, stats + 256);
  bnfin_kernel<<<1, 128, 0, stream>>>(stats + 256, g1, be1, bnp + 256);

  layer2_mfma<<<NB1_, 256, 0, stream>>>(x1, bnp + 256, W2b, b2, ymaxo, ymino, part2);
  reduce1<<<64, 256, 0, stream>>>(part2, R1_, mid + 2 * 64 * 256);
  reduce2<<<1, 256, 0, stream>>>(mid + 2 * 64 * 256, stats + 512);
  bnfin_kernel<<<1, 128, 0, stream>>>(stats + 512, g2, be2, bnp + 512);

  final_kernel<<<B_ * N_ / 64, 256, 0, stream>>>(ymaxo, ymino, bnp + 512, out);
}